// Round 20
// baseline (298.053 us; speedup 1.0000x reference)
//
#include <hip/hip_runtime.h>
#include <cstdint>
#include <math.h>

#define NB 32
#define NC 256
#define NH 56
#define NW 56
#define OHH 28
#define OWW 28
#define NG 4
#define EPSV 1e-5

static constexpr int HW   = NH * NW;       // 3136
static constexpr int OHW  = OHH * OWW;     // 784
static constexpr int NOUT = NB * NC * OHW; // 6422528
static constexpr int NRED = NB * OHW;      // 25088
static constexpr int QW   = OHW / 4;       // 196
static constexpr int PTILE = 56;           // conv2 pixel tile (784 = 14*56)

// Hedge zone (validated round 9): |x1| < TAU1 -> contribute 0.5*sign to conv2.
#define TAU1 2e-5f

// gstat layout (u64): [0..255] sum1, [256..511] sumsq1, [512..767] sum2, [768..1023] sumsq2

// ---------------------------------------------------------------------------
// K1: pack sign bits of x (bit = v >= 0), float4: 4 pixels per thread
__global__ void pack_x_k(const float* __restrict__ x,
                         unsigned long long* __restrict__ xbits) {
    int idx = blockIdx.x * blockDim.x + threadIdx.x; // NB*NG*HW/4
    int wq = idx % (NW / 4);
    int h  = (idx / (NW / 4)) % NH;
    int g  = (idx / (NW / 4 * NH)) % NG;
    int b  = idx / (NW / 4 * NH * NG);
    const float* xp = x + (((size_t)b * NC + g * 64) * NH + h) * NW + wq * 4;
    unsigned long long b0 = 0, b1 = 0, b2 = 0, b3 = 0;
#pragma unroll
    for (int ci = 0; ci < 64; ++ci) {
        float4 v = *(const float4*)(xp + (size_t)ci * HW);
        b0 |= (unsigned long long)(v.x >= 0.0f) << ci;
        b1 |= (unsigned long long)(v.y >= 0.0f) << ci;
        b2 |= (unsigned long long)(v.z >= 0.0f) << ci;
        b3 |= (unsigned long long)(v.w >= 0.0f) << ci;
    }
    unsigned long long* dst = xbits + ((size_t)(b * NG + g) * NH + h) * NW + wq * 4;
    dst[0] = b0; dst[1] = b1; dst[2] = b2; dst[3] = b3;
}

// K2: pack w1 + w2 sign bits + ZERO the atomic stat accumulators.
__global__ void pack_w_k(const float* __restrict__ w1,
                         const float* __restrict__ w2,
                         unsigned long long* __restrict__ wbits,
                         unsigned long long* __restrict__ w2bits,
                         unsigned long long* __restrict__ gstat) {
    int idx = blockIdx.x * blockDim.x + threadIdx.x; // 3328 exactly
    if (idx < 1024) gstat[idx] = 0ull;
    if (idx < 2304) {
        int tap = idx % 9;
        int co  = idx / 9;
        const float* wp = w1 + (size_t)co * 64 * 9 + tap;
        unsigned long long bits = 0;
#pragma unroll
        for (int ci = 0; ci < 64; ++ci)
            bits |= (unsigned long long)(wp[ci * 9] >= 0.0f) << ci;
        wbits[idx] = bits;
    } else {
        int i2 = idx - 2304;         // 0..1023
        int k  = i2 % 4;
        int co = i2 / 4;
        const float* p = w2 + (size_t)co * 256 + k * 64;
        unsigned long long bits = 0;
#pragma unroll
        for (int ci = 0; ci < 64; ++ci)
            bits |= (unsigned long long)(p[ci] >= 0.0f) << ci;
        w2bits[i2] = bits;
    }
}

// K3: LDS-broadcast popcount grouped 3x3 conv + FUSED BN1 stats (atomics).
__global__ void __launch_bounds__(256) conv1_lds(
        const unsigned long long* __restrict__ xbits,
        const unsigned long long* __restrict__ wbits,
        short* __restrict__ y1,
        unsigned long long* __restrict__ gstat) {
    int blk = blockIdx.x;          // NB*NG*7
    int s7  = blk % 7;             // strip: output rows s7*4 .. s7*4+3
    int g   = (blk / 7) & 3;
    int b   = blk / 28;
    int tid = threadIdx.x;
    int co  = tid & 63;            // lane = channel in group
    int ohl = tid >> 6;            // 0..3

    __shared__ unsigned long long xs[9 * 57];      // [row][col0 = iw=-1 pad]
    __shared__ short ybuf[64][114];                // 112 data + 2 pad
    __shared__ int ssum[4][64];
    __shared__ int ssumsq[4][64];

    int ih0 = s7 * 8 - 1;
    const unsigned long long* xb = xbits + (size_t)(b * NG + g) * HW;
    for (int i = tid; i < 9 * 57; i += 256) {
        int r  = i / 57;
        int cc = i % 57;
        int ih = ih0 + r;
        unsigned long long v = 0;
        if (cc > 0 && (unsigned)ih < (unsigned)NH) v = xb[ih * NW + (cc - 1)];
        xs[i] = v;
    }
    __syncthreads();

    int coG = g * 64 + co;
    const unsigned long long* wb = wbits + coG * 9;
    unsigned long long w0 = wb[0], w1 = wb[1], w2 = wb[2],
                       w3 = wb[3], w4 = wb[4], w5 = wb[5],
                       w6 = wb[6], w7 = wb[7], w8 = wb[8];
    int oh = s7 * 4 + ohl;
    int t0 = 64 - 2 * __popcll(w0), t1 = 64 - 2 * __popcll(w1), t2 = 64 - 2 * __popcll(w2);
    int t3 = 64 - 2 * __popcll(w3), t6 = 64 - 2 * __popcll(w6);
    int base9   = 576 - ((oh == 0) ? (t0 + t1 + t2) : 0);
    int colcorr = t3 + t6 + ((oh == 0) ? 0 : t0);

    const unsigned long long* r0 = xs + (2 * ohl + 0) * 57;
    const unsigned long long* r1 = xs + (2 * ohl + 1) * 57;
    const unsigned long long* r2 = xs + (2 * ohl + 2) * 57;
    short* yrow = &ybuf[co][ohl * 28];
    int isum = 0, isumsq = 0;
    for (int ow = 0; ow < OWW; ++ow) {
        int cbase = ow * 2;
        int acc = __popcll(r0[cbase] ^ w0) + __popcll(r0[cbase + 1] ^ w1) + __popcll(r0[cbase + 2] ^ w2)
                + __popcll(r1[cbase] ^ w3) + __popcll(r1[cbase + 1] ^ w4) + __popcll(r1[cbase + 2] ^ w5)
                + __popcll(r2[cbase] ^ w6) + __popcll(r2[cbase + 1] ^ w7) + __popcll(r2[cbase + 2] ^ w8);
        int y = base9 - ((ow == 0) ? colcorr : 0) - 2 * acc;
        yrow[ow] = (short)y;
        isum   += y;
        isumsq += y * y;
    }
    ssum[ohl][co]   = isum;
    ssumsq[ohl][co] = isumsq;
    __syncthreads();

    for (int i = tid; i < 64 * 112; i += 256) {
        int c2 = i / 112;
        int j  = i % 112;
        y1[((size_t)(b * NC + g * 64 + c2) * OHH + s7 * 4) * OWW + j] =
            ybuf[c2][j];
    }
    if (ohl == 0) {
        long long s  = (long long)ssum[0][co] + ssum[1][co] + ssum[2][co] + ssum[3][co];
        long long sq = (long long)ssumsq[0][co] + ssumsq[1][co] + ssumsq[2][co] + ssumsq[3][co];
        atomicAdd(&gstat[coG],       (unsigned long long)s);
        atomicAdd(&gstat[256 + coG], (unsigned long long)sq);
    }
}

// K4: x1 = BN1(y1) + maxpool3x3s2p1(x); BN1 scale/shift inline from exact sums.
__global__ void __launch_bounds__(256) x1_lds(
        const short* __restrict__ y1,
        const float* __restrict__ x,
        const unsigned long long* __restrict__ gstat,
        const float* __restrict__ g1,
        const float* __restrict__ b1,
        float* __restrict__ out) {
    int blk = blockIdx.x;            // b*NC + c
    int c   = blk & 255;
    int tid = threadIdx.x;
    __shared__ float xs[HW];         // 12.5 KB
    const float4* xp4 = (const float4*)(x + (size_t)blk * HW);
    float4* xs4 = (float4*)xs;
    for (int i = tid; i < HW / 4; i += 256) xs4[i] = xp4[i];
    __syncthreads();
    long long s1v = (long long)gstat[c];
    long long s2v = (long long)gstat[256 + c];
    double n    = (double)NRED;
    double mean = (double)s1v / n;
    double var  = (double)s2v / n - mean * mean;
    double inv  = 1.0 / sqrt(var + EPSV);
    double sc   = (double)g1[c] * inv;
    double sh   = (double)b1[c] - mean * sc;
    const short* yp = y1 + (size_t)blk * OHW;
    float* op = out + (size_t)blk * OHW;
    for (int s = tid; s < OHW; s += 256) {
        int oh = s / OWW, ow = s % OWW;
        float m = -3.4e38f;
#pragma unroll
        for (int kh = 0; kh < 3; ++kh) {
            int ih = oh * 2 - 1 + kh;
            if ((unsigned)ih >= (unsigned)NH) continue;
#pragma unroll
            for (int kw = 0; kw < 3; ++kw) {
                int iw = ow * 2 - 1 + kw;
                if ((unsigned)iw >= (unsigned)NW) continue;
                m = fmaxf(m, xs[ih * NW + iw]);
            }
        }
        op[s] = (float)((double)yp[s] * sc + sh + (double)m);
    }
}

// K5: FUSED ballot-pack + popcount 1x1 conv + FUSED BN2 stats (shfl + atomics).
__global__ void __launch_bounds__(256) conv2f_lds(
        const float* __restrict__ x1,
        const unsigned long long* __restrict__ w2bits,
        short* __restrict__ z2,
        unsigned long long* __restrict__ gstat) {
    int blk  = blockIdx.x;         // b*14 + t
    int t    = blk % 14;
    int b    = blk / 14;
    int tid  = threadIdx.x;
    int lane = tid & 63;
    int w    = tid >> 6;           // 0..3 = channel group
    int s0   = t * PTILE;
    __shared__ float xs[NC][PTILE + 1];                // 58.4 KB
    __shared__ unsigned long long bitsL[4][PTILE];
    __shared__ unsigned long long hedgeL[4][PTILE];

    {
        const float4* src = (const float4*)(x1 + ((size_t)b * NC + tid) * OHW + s0);
        float* dst = xs[tid];
#pragma unroll
        for (int q = 0; q < 14; ++q) {
            float4 v = src[q];
            dst[q * 4 + 0] = v.x; dst[q * 4 + 1] = v.y;
            dst[q * 4 + 2] = v.z; dst[q * 4 + 3] = v.w;
        }
    }
    __syncthreads();

    for (int px = 0; px < PTILE; ++px) {
        float v = xs[w * 64 + lane][px];
        unsigned long long bb = __ballot(v >= 0.0f);
        unsigned long long hh = __ballot(fabsf(v) < TAU1);
        if (lane == 0) { bitsL[w][px] = bb; hedgeL[w][px] = hh; }
    }
    __syncthreads();

    for (int it = 0; it < 64; ++it) {
        int co = it * 4 + w;
        const unsigned long long* wb = w2bits + co * 4;
        unsigned long long wv0 = wb[0], wv1 = wb[1], wv2 = wb[2], wv3 = wb[3];
        int zv = 0, zsq = 0;
        if (lane < PTILE) {
            unsigned long long d0 = bitsL[0][lane] ^ wv0, d1 = bitsL[1][lane] ^ wv1,
                               d2 = bitsL[2][lane] ^ wv2, d3 = bitsL[3][lane] ^ wv3;
            unsigned long long h0 = hedgeL[0][lane], h1 = hedgeL[1][lane],
                               h2 = hedgeL[2][lane], h3 = hedgeL[3][lane];
            int full = 256 - 2 * (__popcll(d0) + __popcll(d1) + __popcll(d2) + __popcll(d3));
            int hcorr = __popcll(h0) + __popcll(h1) + __popcll(h2) + __popcll(h3)
                      - 2 * (__popcll(h0 & d0) + __popcll(h1 & d1) +
                             __popcll(h2 & d2) + __popcll(h3 & d3));
            int zz = 2 * full - hcorr;
            z2[((size_t)b * NC + co) * OHW + s0 + lane] = (short)zz;
            zv  = zz;
            zsq = zz * zz;
        }
        // wave-reduce (z, z^2) across 64 lanes (inactive lanes contribute 0)
#pragma unroll
        for (int off = 1; off < 64; off <<= 1) {
            zv  += __shfl_xor(zv,  off);
            zsq += __shfl_xor(zsq, off);
        }
        if (lane == 0) {
            atomicAdd(&gstat[512 + co], (unsigned long long)(long long)zv);
            atomicAdd(&gstat[768 + co], (unsigned long long)zsq);
        }
    }
}

// K6: out = BN2(z) + x1; BN2 scale/shift inline from exact sums (vdiv=2).
__global__ void final_k(const short* __restrict__ z2,
                        const unsigned long long* __restrict__ gstat,
                        const float* __restrict__ g2,
                        const float* __restrict__ b2,
                        float* __restrict__ out) {
    int idx = blockIdx.x * blockDim.x + threadIdx.x;   // NOUT/4
    int c = (idx / QW) % NC;
    long long s1v = (long long)gstat[512 + c];
    long long s2v = (long long)gstat[768 + c];
    double n    = (double)NRED;
    double mean = (double)s1v / (n * 2.0);
    double var  = (double)s2v / (n * 2.0 * 2.0) - mean * mean;
    double inv  = 1.0 / sqrt(var + EPSV);
    double sc   = (double)g2[c] * inv;
    double sh   = (double)b2[c] - mean * sc;
    short4 zz = ((const short4*)z2)[idx];
    float4 o  = ((const float4*)out)[idx];
    o.x = (float)((double)zz.x * 0.5 * sc + sh + (double)o.x);
    o.y = (float)((double)zz.y * 0.5 * sc + sh + (double)o.y);
    o.z = (float)((double)zz.z * 0.5 * sc + sh + (double)o.z);
    o.w = (float)((double)zz.w * 0.5 * sc + sh + (double)o.w);
    ((float4*)out)[idx] = o;
}

// ---------------------------------------------------------------------------
extern "C" void kernel_launch(void* const* d_in, const int* in_sizes, int n_in,
                              void* d_out, int out_size, void* d_ws, size_t ws_size,
                              hipStream_t stream) {
    const float* x  = (const float*)d_in[0];
    const float* w1 = (const float*)d_in[1];
    const float* g1 = (const float*)d_in[2];
    const float* b1 = (const float*)d_in[3];
    const float* w2 = (const float*)d_in[4];
    const float* g2 = (const float*)d_in[5];
    const float* b2 = (const float*)d_in[6];
    float* out = (float*)d_out;

    char* ws = (char*)d_ws;
    auto alloc = [&](size_t bytes) -> char* {
        char* p = ws;
        ws += (bytes + 255) & ~(size_t)255;
        return p;
    };

    unsigned long long* xbits   = (unsigned long long*)alloc((size_t)NB * NG * HW * 8);
    unsigned long long* wbits1  = (unsigned long long*)alloc((size_t)NC * 9 * 8);
    unsigned long long* w2bits  = (unsigned long long*)alloc((size_t)NC * 4 * 8);
    unsigned long long* gstat   = (unsigned long long*)alloc(1024 * 8);
    short*              y1      = (short*)alloc((size_t)NOUT * 2);
    short*              z2buf   = (short*)alloc((size_t)NOUT * 2);

    const int T = 256;

    pack_x_k  <<<(NB * NG * HW / 4) / T, T, 0, stream>>>(x, xbits);
    pack_w_k  <<<13,                     T, 0, stream>>>(w1, w2, wbits1, w2bits, gstat);
    conv1_lds <<<NB * NG * 7,            T, 0, stream>>>(xbits, wbits1, y1, gstat);
    x1_lds    <<<NB * NC,                T, 0, stream>>>(y1, x, gstat, g1, b1, out);
    conv2f_lds<<<NB * 14,                T, 0, stream>>>(out, w2bits, z2buf, gstat);
    final_k   <<<(NOUT / 4) / T,         T, 0, stream>>>(z2buf, gstat, g2, b2, out);
}

// Round 21
// 118.723 us; speedup vs baseline: 2.5105x; 2.5105x over previous
//
#include <hip/hip_runtime.h>
#include <cstdint>
#include <math.h>

#define NB 32
#define NC 256
#define NH 56
#define NW 56
#define OHH 28
#define OWW 28
#define NG 4
#define EPSV 1e-5

static constexpr int HW   = NH * NW;       // 3136
static constexpr int OHW  = OHH * OWW;     // 784
static constexpr int NOUT = NB * NC * OHW; // 6422528
static constexpr int NRED = NB * OHW;      // 25088
static constexpr int QW   = OHW / 4;       // 196
static constexpr int PTILE = 56;           // conv2 pixel tile (784 = 14*56)

// Hedge zone (validated round 9): |x1| < TAU1 -> contribute 0.5*sign to conv2.
#define TAU1 2e-5f

// gstat layout (u64): [0..255] sum1, [256..511] sumsq1, [512..767] sum2, [768..1023] sumsq2

// ---------------------------------------------------------------------------
// K1: pack sign bits of x (bit = v >= 0), float4: 4 pixels per thread
__global__ void pack_x_k(const float* __restrict__ x,
                         unsigned long long* __restrict__ xbits) {
    int idx = blockIdx.x * blockDim.x + threadIdx.x; // NB*NG*HW/4
    int wq = idx % (NW / 4);
    int h  = (idx / (NW / 4)) % NH;
    int g  = (idx / (NW / 4 * NH)) % NG;
    int b  = idx / (NW / 4 * NH * NG);
    const float* xp = x + (((size_t)b * NC + g * 64) * NH + h) * NW + wq * 4;
    unsigned long long b0 = 0, b1 = 0, b2 = 0, b3 = 0;
#pragma unroll
    for (int ci = 0; ci < 64; ++ci) {
        float4 v = *(const float4*)(xp + (size_t)ci * HW);
        b0 |= (unsigned long long)(v.x >= 0.0f) << ci;
        b1 |= (unsigned long long)(v.y >= 0.0f) << ci;
        b2 |= (unsigned long long)(v.z >= 0.0f) << ci;
        b3 |= (unsigned long long)(v.w >= 0.0f) << ci;
    }
    unsigned long long* dst = xbits + ((size_t)(b * NG + g) * NH + h) * NW + wq * 4;
    dst[0] = b0; dst[1] = b1; dst[2] = b2; dst[3] = b3;
}

// K2: pack w1 + w2 sign bits + ZERO the atomic stat accumulators.
__global__ void pack_w_k(const float* __restrict__ w1,
                         const float* __restrict__ w2,
                         unsigned long long* __restrict__ wbits,
                         unsigned long long* __restrict__ w2bits,
                         unsigned long long* __restrict__ gstat) {
    int idx = blockIdx.x * blockDim.x + threadIdx.x; // 3328 exactly
    if (idx < 1024) gstat[idx] = 0ull;
    if (idx < 2304) {
        int tap = idx % 9;
        int co  = idx / 9;
        const float* wp = w1 + (size_t)co * 64 * 9 + tap;
        unsigned long long bits = 0;
#pragma unroll
        for (int ci = 0; ci < 64; ++ci)
            bits |= (unsigned long long)(wp[ci * 9] >= 0.0f) << ci;
        wbits[idx] = bits;
    } else {
        int i2 = idx - 2304;         // 0..1023
        int k  = i2 % 4;
        int co = i2 / 4;
        const float* p = w2 + (size_t)co * 256 + k * 64;
        unsigned long long bits = 0;
#pragma unroll
        for (int ci = 0; ci < 64; ++ci)
            bits |= (unsigned long long)(p[ci] >= 0.0f) << ci;
        w2bits[i2] = bits;
    }
}

// K3: LDS-broadcast popcount grouped 3x3 conv + FUSED BN1 stats (atomics).
__global__ void __launch_bounds__(256) conv1_lds(
        const unsigned long long* __restrict__ xbits,
        const unsigned long long* __restrict__ wbits,
        short* __restrict__ y1,
        unsigned long long* __restrict__ gstat) {
    int blk = blockIdx.x;          // NB*NG*7
    int s7  = blk % 7;             // strip: output rows s7*4 .. s7*4+3
    int g   = (blk / 7) & 3;
    int b   = blk / 28;
    int tid = threadIdx.x;
    int co  = tid & 63;            // lane = channel in group
    int ohl = tid >> 6;            // 0..3

    __shared__ unsigned long long xs[9 * 57];      // [row][col0 = iw=-1 pad]
    __shared__ short ybuf[64][114];                // 112 data + 2 pad
    __shared__ int ssum[4][64];
    __shared__ int ssumsq[4][64];

    int ih0 = s7 * 8 - 1;
    const unsigned long long* xb = xbits + (size_t)(b * NG + g) * HW;
    for (int i = tid; i < 9 * 57; i += 256) {
        int r  = i / 57;
        int cc = i % 57;
        int ih = ih0 + r;
        unsigned long long v = 0;
        if (cc > 0 && (unsigned)ih < (unsigned)NH) v = xb[ih * NW + (cc - 1)];
        xs[i] = v;
    }
    __syncthreads();

    int coG = g * 64 + co;
    const unsigned long long* wb = wbits + coG * 9;
    unsigned long long w0 = wb[0], w1 = wb[1], w2 = wb[2],
                       w3 = wb[3], w4 = wb[4], w5 = wb[5],
                       w6 = wb[6], w7 = wb[7], w8 = wb[8];
    int oh = s7 * 4 + ohl;
    int t0 = 64 - 2 * __popcll(w0), t1 = 64 - 2 * __popcll(w1), t2 = 64 - 2 * __popcll(w2);
    int t3 = 64 - 2 * __popcll(w3), t6 = 64 - 2 * __popcll(w6);
    int base9   = 576 - ((oh == 0) ? (t0 + t1 + t2) : 0);
    int colcorr = t3 + t6 + ((oh == 0) ? 0 : t0);

    const unsigned long long* r0 = xs + (2 * ohl + 0) * 57;
    const unsigned long long* r1 = xs + (2 * ohl + 1) * 57;
    const unsigned long long* r2 = xs + (2 * ohl + 2) * 57;
    short* yrow = &ybuf[co][ohl * 28];
    int isum = 0, isumsq = 0;
    for (int ow = 0; ow < OWW; ++ow) {
        int cbase = ow * 2;
        int acc = __popcll(r0[cbase] ^ w0) + __popcll(r0[cbase + 1] ^ w1) + __popcll(r0[cbase + 2] ^ w2)
                + __popcll(r1[cbase] ^ w3) + __popcll(r1[cbase + 1] ^ w4) + __popcll(r1[cbase + 2] ^ w5)
                + __popcll(r2[cbase] ^ w6) + __popcll(r2[cbase + 1] ^ w7) + __popcll(r2[cbase + 2] ^ w8);
        int y = base9 - ((ow == 0) ? colcorr : 0) - 2 * acc;
        yrow[ow] = (short)y;
        isum   += y;
        isumsq += y * y;
    }
    ssum[ohl][co]   = isum;
    ssumsq[ohl][co] = isumsq;
    __syncthreads();

    for (int i = tid; i < 64 * 112; i += 256) {
        int c2 = i / 112;
        int j  = i % 112;
        y1[((size_t)(b * NC + g * 64 + c2) * OHH + s7 * 4) * OWW + j] =
            ybuf[c2][j];
    }
    if (ohl == 0) {
        long long s  = (long long)ssum[0][co] + ssum[1][co] + ssum[2][co] + ssum[3][co];
        long long sq = (long long)ssumsq[0][co] + ssumsq[1][co] + ssumsq[2][co] + ssumsq[3][co];
        atomicAdd(&gstat[coG],       (unsigned long long)s);
        atomicAdd(&gstat[256 + coG], (unsigned long long)sq);
    }
}

// K4: x1 = BN1(y1) + maxpool3x3s2p1(x); BN1 scale/shift inline from exact sums.
__global__ void __launch_bounds__(256) x1_lds(
        const short* __restrict__ y1,
        const float* __restrict__ x,
        const unsigned long long* __restrict__ gstat,
        const float* __restrict__ g1,
        const float* __restrict__ b1,
        float* __restrict__ out) {
    int blk = blockIdx.x;            // b*NC + c
    int c   = blk & 255;
    int tid = threadIdx.x;
    __shared__ float xs[HW];         // 12.5 KB
    const float4* xp4 = (const float4*)(x + (size_t)blk * HW);
    float4* xs4 = (float4*)xs;
    for (int i = tid; i < HW / 4; i += 256) xs4[i] = xp4[i];
    __syncthreads();
    long long s1v = (long long)gstat[c];
    long long s2v = (long long)gstat[256 + c];
    double n    = (double)NRED;
    double mean = (double)s1v / n;
    double var  = (double)s2v / n - mean * mean;
    double inv  = 1.0 / sqrt(var + EPSV);
    double sc   = (double)g1[c] * inv;
    double sh   = (double)b1[c] - mean * sc;
    const short* yp = y1 + (size_t)blk * OHW;
    float* op = out + (size_t)blk * OHW;
    for (int s = tid; s < OHW; s += 256) {
        int oh = s / OWW, ow = s % OWW;
        float m = -3.4e38f;
#pragma unroll
        for (int kh = 0; kh < 3; ++kh) {
            int ih = oh * 2 - 1 + kh;
            if ((unsigned)ih >= (unsigned)NH) continue;
#pragma unroll
            for (int kw = 0; kw < 3; ++kw) {
                int iw = ow * 2 - 1 + kw;
                if ((unsigned)iw >= (unsigned)NW) continue;
                m = fmaxf(m, xs[ih * NW + iw]);
            }
        }
        op[s] = (float)((double)yp[s] * sc + sh + (double)m);
    }
}

// K5: FUSED ballot-pack + popcount 1x1 conv + BN2 stats via LDS-transpose
// register reduce (NO cross-lane shuffles, atomics once at block end).
// The z transpose buffer ALIASES the dead x1-float staging region.
__global__ void __launch_bounds__(256) conv2f_lds(
        const float* __restrict__ x1,
        const unsigned long long* __restrict__ w2bits,
        short* __restrict__ z2,
        unsigned long long* __restrict__ gstat) {
    int blk  = blockIdx.x;         // b*14 + t
    int t    = blk % 14;
    int b    = blk / 14;
    int tid  = threadIdx.x;
    int lane = tid & 63;
    int w    = tid >> 6;           // 0..3 = channel group
    int s0   = t * PTILE;
    __shared__ __align__(16) char smemA[NC * (PTILE + 1) * 4];   // 58.4 KB
    float (*xs)[PTILE + 1]  = (float (*)[PTILE + 1])smemA;       // live: stage+ballot
    short (*ztr)[PTILE + 1] = (short (*)[PTILE + 1])smemA;       // live: sweep+reduce
    __shared__ unsigned long long bitsL[4][PTILE];
    __shared__ unsigned long long hedgeL[4][PTILE];

    {
        const float4* src = (const float4*)(x1 + ((size_t)b * NC + tid) * OHW + s0);
        float* dst = xs[tid];
#pragma unroll
        for (int q = 0; q < 14; ++q) {
            float4 v = src[q];
            dst[q * 4 + 0] = v.x; dst[q * 4 + 1] = v.y;
            dst[q * 4 + 2] = v.z; dst[q * 4 + 3] = v.w;
        }
    }
    __syncthreads();

    for (int px = 0; px < PTILE; ++px) {
        float v = xs[w * 64 + lane][px];
        unsigned long long bb = __ballot(v >= 0.0f);
        unsigned long long hh = __ballot(fabsf(v) < TAU1);
        if (lane == 0) { bitsL[w][px] = bb; hedgeL[w][px] = hh; }
    }
    __syncthreads();               // xs dead beyond this point; ztr takes over

    for (int it = 0; it < 64; ++it) {
        int co = it * 4 + w;
        const unsigned long long* wb = w2bits + co * 4;
        unsigned long long wv0 = wb[0], wv1 = wb[1], wv2 = wb[2], wv3 = wb[3];
        if (lane < PTILE) {
            unsigned long long d0 = bitsL[0][lane] ^ wv0, d1 = bitsL[1][lane] ^ wv1,
                               d2 = bitsL[2][lane] ^ wv2, d3 = bitsL[3][lane] ^ wv3;
            unsigned long long h0 = hedgeL[0][lane], h1 = hedgeL[1][lane],
                               h2 = hedgeL[2][lane], h3 = hedgeL[3][lane];
            int full = 256 - 2 * (__popcll(d0) + __popcll(d1) + __popcll(d2) + __popcll(d3));
            int hcorr = __popcll(h0) + __popcll(h1) + __popcll(h2) + __popcll(h3)
                      - 2 * (__popcll(h0 & d0) + __popcll(h1 & d1) +
                             __popcll(h2 & d2) + __popcll(h3 & d3));
            int zz = 2 * full - hcorr;
            z2[((size_t)b * NC + co) * OHW + s0 + lane] = (short)zz;
            ztr[co][lane] = (short)zz;
        }
    }
    __syncthreads();

    // per-channel partial stats: thread tid = channel; register reduce from LDS
    {
        int zsum = 0, zsq = 0;
#pragma unroll
        for (int j = 0; j < PTILE; ++j) {
            int zz = ztr[tid][j];
            zsum += zz;
            zsq  += zz * zz;
        }
        atomicAdd(&gstat[512 + tid], (unsigned long long)(long long)zsum);
        atomicAdd(&gstat[768 + tid], (unsigned long long)zsq);
    }
}

// K6: out = BN2(z) + x1; BN2 scale/shift inline from exact sums (vdiv=2).
__global__ void final_k(const short* __restrict__ z2,
                        const unsigned long long* __restrict__ gstat,
                        const float* __restrict__ g2,
                        const float* __restrict__ b2,
                        float* __restrict__ out) {
    int idx = blockIdx.x * blockDim.x + threadIdx.x;   // NOUT/4
    int c = (idx / QW) % NC;
    long long s1v = (long long)gstat[512 + c];
    long long s2v = (long long)gstat[768 + c];
    double n    = (double)NRED;
    double mean = (double)s1v / (n * 2.0);
    double var  = (double)s2v / (n * 2.0 * 2.0) - mean * mean;
    double inv  = 1.0 / sqrt(var + EPSV);
    double sc   = (double)g2[c] * inv;
    double sh   = (double)b2[c] - mean * sc;
    short4 zz = ((const short4*)z2)[idx];
    float4 o  = ((const float4*)out)[idx];
    o.x = (float)((double)zz.x * 0.5 * sc + sh + (double)o.x);
    o.y = (float)((double)zz.y * 0.5 * sc + sh + (double)o.y);
    o.z = (float)((double)zz.z * 0.5 * sc + sh + (double)o.z);
    o.w = (float)((double)zz.w * 0.5 * sc + sh + (double)o.w);
    ((float4*)out)[idx] = o;
}

// ---------------------------------------------------------------------------
extern "C" void kernel_launch(void* const* d_in, const int* in_sizes, int n_in,
                              void* d_out, int out_size, void* d_ws, size_t ws_size,
                              hipStream_t stream) {
    const float* x  = (const float*)d_in[0];
    const float* w1 = (const float*)d_in[1];
    const float* g1 = (const float*)d_in[2];
    const float* b1 = (const float*)d_in[3];
    const float* w2 = (const float*)d_in[4];
    const float* g2 = (const float*)d_in[5];
    const float* b2 = (const float*)d_in[6];
    float* out = (float*)d_out;

    char* ws = (char*)d_ws;
    auto alloc = [&](size_t bytes) -> char* {
        char* p = ws;
        ws += (bytes + 255) & ~(size_t)255;
        return p;
    };

    unsigned long long* xbits   = (unsigned long long*)alloc((size_t)NB * NG * HW * 8);
    unsigned long long* wbits1  = (unsigned long long*)alloc((size_t)NC * 9 * 8);
    unsigned long long* w2bits  = (unsigned long long*)alloc((size_t)NC * 4 * 8);
    unsigned long long* gstat   = (unsigned long long*)alloc(1024 * 8);
    short*              y1      = (short*)alloc((size_t)NOUT * 2);
    short*              z2buf   = (short*)alloc((size_t)NOUT * 2);

    const int T = 256;

    pack_x_k  <<<(NB * NG * HW / 4) / T, T, 0, stream>>>(x, xbits);
    pack_w_k  <<<13,                     T, 0, stream>>>(w1, w2, wbits1, w2bits, gstat);
    conv1_lds <<<NB * NG * 7,            T, 0, stream>>>(xbits, wbits1, y1, gstat);
    x1_lds    <<<NB * NC,                T, 0, stream>>>(y1, x, gstat, g1, b1, out);
    conv2f_lds<<<NB * 14,                T, 0, stream>>>(out, w2bits, z2buf, gstat);
    final_k   <<<(NOUT / 4) / T,         T, 0, stream>>>(z2buf, gstat, g2, b2, out);
}

// Round 22
// 115.707 us; speedup vs baseline: 2.5759x; 1.0261x over previous
//
#include <hip/hip_runtime.h>
#include <cstdint>
#include <math.h>

#define NB 32
#define NC 256
#define NH 56
#define NW 56
#define OHH 28
#define OWW 28
#define NG 4
#define EPSV 1e-5

static constexpr int HW   = NH * NW;       // 3136
static constexpr int OHW  = OHH * OWW;     // 784
static constexpr int NOUT = NB * NC * OHW; // 6422528
static constexpr int NRED = NB * OHW;      // 25088
static constexpr int QW   = OHW / 4;       // 196
static constexpr int PTILE = 56;           // conv2 pixel tile (784 = 14*56)
static constexpr int PXBLK = NB * NG * HW / 4 / 256;  // 6272 pack_x blocks

// Hedge zone (validated round 9): |x1| < TAU1 -> contribute 0.5*sign to conv2.
#define TAU1 2e-5f

// gstat layout (u64): [0..255] sum1, [256..511] sumsq1, [512..767] sum2, [768..1023] sumsq2

// ---------------------------------------------------------------------------
// K1: MERGED pack: blocks [0,6272) pack x sign bits (float4, 4 px/thread);
// blocks [6272,6285) pack w1+w2 sign bits and zero the gstat accumulators.
__global__ void pack_all_k(const float* __restrict__ x,
                           const float* __restrict__ w1,
                           const float* __restrict__ w2,
                           unsigned long long* __restrict__ xbits,
                           unsigned long long* __restrict__ wbits,
                           unsigned long long* __restrict__ w2bits,
                           unsigned long long* __restrict__ gstat) {
    if (blockIdx.x < PXBLK) {
        int idx = blockIdx.x * blockDim.x + threadIdx.x; // NB*NG*HW/4
        int wq = idx % (NW / 4);
        int h  = (idx / (NW / 4)) % NH;
        int g  = (idx / (NW / 4 * NH)) % NG;
        int b  = idx / (NW / 4 * NH * NG);
        const float* xp = x + (((size_t)b * NC + g * 64) * NH + h) * NW + wq * 4;
        unsigned long long b0 = 0, b1 = 0, b2 = 0, b3 = 0;
#pragma unroll
        for (int ci = 0; ci < 64; ++ci) {
            float4 v = *(const float4*)(xp + (size_t)ci * HW);
            b0 |= (unsigned long long)(v.x >= 0.0f) << ci;
            b1 |= (unsigned long long)(v.y >= 0.0f) << ci;
            b2 |= (unsigned long long)(v.z >= 0.0f) << ci;
            b3 |= (unsigned long long)(v.w >= 0.0f) << ci;
        }
        unsigned long long* dst = xbits + ((size_t)(b * NG + g) * NH + h) * NW + wq * 4;
        dst[0] = b0; dst[1] = b1; dst[2] = b2; dst[3] = b3;
    } else {
        int idx = (blockIdx.x - PXBLK) * blockDim.x + threadIdx.x; // 0..3327
        if (idx < 1024) gstat[idx] = 0ull;
        if (idx < 2304) {
            int tap = idx % 9;
            int co  = idx / 9;
            const float* wp = w1 + (size_t)co * 64 * 9 + tap;
            unsigned long long bits = 0;
#pragma unroll
            for (int ci = 0; ci < 64; ++ci)
                bits |= (unsigned long long)(wp[ci * 9] >= 0.0f) << ci;
            wbits[idx] = bits;
        } else {
            int i2 = idx - 2304;         // 0..1023
            int k  = i2 % 4;
            int co = i2 / 4;
            const float* p = w2 + (size_t)co * 256 + k * 64;
            unsigned long long bits = 0;
#pragma unroll
            for (int ci = 0; ci < 64; ++ci)
                bits |= (unsigned long long)(p[ci] >= 0.0f) << ci;
            w2bits[i2] = bits;
        }
    }
}

// K2: LDS-broadcast popcount grouped 3x3 conv + FUSED BN1 stats (atomics).
__global__ void __launch_bounds__(256) conv1_lds(
        const unsigned long long* __restrict__ xbits,
        const unsigned long long* __restrict__ wbits,
        short* __restrict__ y1,
        unsigned long long* __restrict__ gstat) {
    int blk = blockIdx.x;          // NB*NG*7
    int s7  = blk % 7;             // strip: output rows s7*4 .. s7*4+3
    int g   = (blk / 7) & 3;
    int b   = blk / 28;
    int tid = threadIdx.x;
    int co  = tid & 63;            // lane = channel in group
    int ohl = tid >> 6;            // 0..3

    __shared__ unsigned long long xs[9 * 57];      // [row][col0 = iw=-1 pad]
    __shared__ short ybuf[64][114];                // 112 data + 2 pad
    __shared__ int ssum[4][64];
    __shared__ int ssumsq[4][64];

    int ih0 = s7 * 8 - 1;
    const unsigned long long* xb = xbits + (size_t)(b * NG + g) * HW;
    for (int i = tid; i < 9 * 57; i += 256) {
        int r  = i / 57;
        int cc = i % 57;
        int ih = ih0 + r;
        unsigned long long v = 0;
        if (cc > 0 && (unsigned)ih < (unsigned)NH) v = xb[ih * NW + (cc - 1)];
        xs[i] = v;
    }
    __syncthreads();

    int coG = g * 64 + co;
    const unsigned long long* wb = wbits + coG * 9;
    unsigned long long w0 = wb[0], w1 = wb[1], w2 = wb[2],
                       w3 = wb[3], w4 = wb[4], w5 = wb[5],
                       w6 = wb[6], w7 = wb[7], w8 = wb[8];
    int oh = s7 * 4 + ohl;
    int t0 = 64 - 2 * __popcll(w0), t1 = 64 - 2 * __popcll(w1), t2 = 64 - 2 * __popcll(w2);
    int t3 = 64 - 2 * __popcll(w3), t6 = 64 - 2 * __popcll(w6);
    int base9   = 576 - ((oh == 0) ? (t0 + t1 + t2) : 0);
    int colcorr = t3 + t6 + ((oh == 0) ? 0 : t0);

    const unsigned long long* r0 = xs + (2 * ohl + 0) * 57;
    const unsigned long long* r1 = xs + (2 * ohl + 1) * 57;
    const unsigned long long* r2 = xs + (2 * ohl + 2) * 57;
    short* yrow = &ybuf[co][ohl * 28];
    int isum = 0, isumsq = 0;
    for (int ow = 0; ow < OWW; ++ow) {
        int cbase = ow * 2;
        int acc = __popcll(r0[cbase] ^ w0) + __popcll(r0[cbase + 1] ^ w1) + __popcll(r0[cbase + 2] ^ w2)
                + __popcll(r1[cbase] ^ w3) + __popcll(r1[cbase + 1] ^ w4) + __popcll(r1[cbase + 2] ^ w5)
                + __popcll(r2[cbase] ^ w6) + __popcll(r2[cbase + 1] ^ w7) + __popcll(r2[cbase + 2] ^ w8);
        int y = base9 - ((ow == 0) ? colcorr : 0) - 2 * acc;
        yrow[ow] = (short)y;
        isum   += y;
        isumsq += y * y;
    }
    ssum[ohl][co]   = isum;
    ssumsq[ohl][co] = isumsq;
    __syncthreads();

    for (int i = tid; i < 64 * 112; i += 256) {
        int c2 = i / 112;
        int j  = i % 112;
        y1[((size_t)(b * NC + g * 64 + c2) * OHH + s7 * 4) * OWW + j] =
            ybuf[c2][j];
    }
    if (ohl == 0) {
        long long s  = (long long)ssum[0][co] + ssum[1][co] + ssum[2][co] + ssum[3][co];
        long long sq = (long long)ssumsq[0][co] + ssumsq[1][co] + ssumsq[2][co] + ssumsq[3][co];
        atomicAdd(&gstat[coG],       (unsigned long long)s);
        atomicAdd(&gstat[256 + coG], (unsigned long long)sq);
    }
}

// K3: x1 = BN1(y1) + maxpool3x3s2p1(x); BN1 scale/shift inline from exact sums.
__global__ void __launch_bounds__(256) x1_lds(
        const short* __restrict__ y1,
        const float* __restrict__ x,
        const unsigned long long* __restrict__ gstat,
        const float* __restrict__ g1,
        const float* __restrict__ b1,
        float* __restrict__ out) {
    int blk = blockIdx.x;            // b*NC + c
    int c   = blk & 255;
    int tid = threadIdx.x;
    __shared__ float xs[HW];         // 12.5 KB
    const float4* xp4 = (const float4*)(x + (size_t)blk * HW);
    float4* xs4 = (float4*)xs;
    for (int i = tid; i < HW / 4; i += 256) xs4[i] = xp4[i];
    __syncthreads();
    long long s1v = (long long)gstat[c];
    long long s2v = (long long)gstat[256 + c];
    double n    = (double)NRED;
    double mean = (double)s1v / n;
    double var  = (double)s2v / n - mean * mean;
    double inv  = 1.0 / sqrt(var + EPSV);
    double sc   = (double)g1[c] * inv;
    double sh   = (double)b1[c] - mean * sc;
    const short* yp = y1 + (size_t)blk * OHW;
    float* op = out + (size_t)blk * OHW;
    for (int s = tid; s < OHW; s += 256) {
        int oh = s / OWW, ow = s % OWW;
        float m = -3.4e38f;
#pragma unroll
        for (int kh = 0; kh < 3; ++kh) {
            int ih = oh * 2 - 1 + kh;
            if ((unsigned)ih >= (unsigned)NH) continue;
#pragma unroll
            for (int kw = 0; kw < 3; ++kw) {
                int iw = ow * 2 - 1 + kw;
                if ((unsigned)iw >= (unsigned)NW) continue;
                m = fmaxf(m, xs[ih * NW + iw]);
            }
        }
        op[s] = (float)((double)yp[s] * sc + sh + (double)m);
    }
}

// K4: FUSED ballot-pack + popcount 1x1 conv + BN2 stats.
// LDS-compact: stage computes 2-bit codes (sign<<1 | hedge) -> bytes, ballots
// read the bytes, and the z-transpose reduce buffer ALIASES the dead code
// region. ~33 KB LDS -> 4 blocks/CU (was 62 KB / 2 blocks).
__global__ void __launch_bounds__(256) conv2f_lds(
        const float* __restrict__ x1,
        const unsigned long long* __restrict__ w2bits,
        short* __restrict__ z2,
        unsigned long long* __restrict__ gstat) {
    int blk  = blockIdx.x;         // b*14 + t
    int t    = blk % 14;
    int b    = blk / 14;
    int tid  = threadIdx.x;
    int lane = tid & 63;
    int w    = tid >> 6;           // 0..3 = channel group
    int s0   = t * PTILE;
    __shared__ __align__(16) char smemU[NC * (PTILE + 1) * 2];   // 29.2 KB union
    unsigned char (*code)[PTILE + 1] = (unsigned char (*)[PTILE + 1])smemU; // stage+ballot
    short (*ztr)[PTILE + 1]          = (short (*)[PTILE + 1])smemU;         // sweep+reduce
    __shared__ unsigned long long bitsL[4][PTILE];
    __shared__ unsigned long long hedgeL[4][PTILE];

    {   // stage: thread = channel; read 56 floats, store 2-bit codes
        const float4* src = (const float4*)(x1 + ((size_t)b * NC + tid) * OHW + s0);
        unsigned char* dst = code[tid];
#pragma unroll
        for (int q = 0; q < 14; ++q) {
            float4 v = src[q];
            dst[q * 4 + 0] = (unsigned char)((v.x >= 0.0f ? 2 : 0) | (fabsf(v.x) < TAU1 ? 1 : 0));
            dst[q * 4 + 1] = (unsigned char)((v.y >= 0.0f ? 2 : 0) | (fabsf(v.y) < TAU1 ? 1 : 0));
            dst[q * 4 + 2] = (unsigned char)((v.z >= 0.0f ? 2 : 0) | (fabsf(v.z) < TAU1 ? 1 : 0));
            dst[q * 4 + 3] = (unsigned char)((v.w >= 0.0f ? 2 : 0) | (fabsf(v.w) < TAU1 ? 1 : 0));
        }
    }
    __syncthreads();

    for (int px = 0; px < PTILE; ++px) {
        unsigned int cv = code[w * 64 + lane][px];
        unsigned long long bb = __ballot((cv & 2u) != 0u);
        unsigned long long hh = __ballot((cv & 1u) != 0u);
        if (lane == 0) { bitsL[w][px] = bb; hedgeL[w][px] = hh; }
    }
    __syncthreads();               // code dead beyond this point; ztr takes over

    for (int it = 0; it < 64; ++it) {
        int co = it * 4 + w;
        const unsigned long long* wb = w2bits + co * 4;
        unsigned long long wv0 = wb[0], wv1 = wb[1], wv2 = wb[2], wv3 = wb[3];
        if (lane < PTILE) {
            unsigned long long d0 = bitsL[0][lane] ^ wv0, d1 = bitsL[1][lane] ^ wv1,
                               d2 = bitsL[2][lane] ^ wv2, d3 = bitsL[3][lane] ^ wv3;
            unsigned long long h0 = hedgeL[0][lane], h1 = hedgeL[1][lane],
                               h2 = hedgeL[2][lane], h3 = hedgeL[3][lane];
            int full = 256 - 2 * (__popcll(d0) + __popcll(d1) + __popcll(d2) + __popcll(d3));
            int hcorr = __popcll(h0) + __popcll(h1) + __popcll(h2) + __popcll(h3)
                      - 2 * (__popcll(h0 & d0) + __popcll(h1 & d1) +
                             __popcll(h2 & d2) + __popcll(h3 & d3));
            int zz = 2 * full - hcorr;
            z2[((size_t)b * NC + co) * OHW + s0 + lane] = (short)zz;
            ztr[co][lane] = (short)zz;
        }
    }
    __syncthreads();

    // per-channel partial stats: thread = channel; register reduce from LDS
    {
        int zsum = 0, zsq = 0;
#pragma unroll
        for (int j = 0; j < PTILE; ++j) {
            int zz = ztr[tid][j];
            zsum += zz;
            zsq  += zz * zz;
        }
        atomicAdd(&gstat[512 + tid], (unsigned long long)(long long)zsum);
        atomicAdd(&gstat[768 + tid], (unsigned long long)zsq);
    }
}

// K5: out = BN2(z) + x1; BN2 scale/shift inline from exact sums (vdiv=2).
__global__ void final_k(const short* __restrict__ z2,
                        const unsigned long long* __restrict__ gstat,
                        const float* __restrict__ g2,
                        const float* __restrict__ b2,
                        float* __restrict__ out) {
    int idx = blockIdx.x * blockDim.x + threadIdx.x;   // NOUT/4
    int c = (idx / QW) % NC;
    long long s1v = (long long)gstat[512 + c];
    long long s2v = (long long)gstat[768 + c];
    double n    = (double)NRED;
    double mean = (double)s1v / (n * 2.0);
    double var  = (double)s2v / (n * 2.0 * 2.0) - mean * mean;
    double inv  = 1.0 / sqrt(var + EPSV);
    double sc   = (double)g2[c] * inv;
    double sh   = (double)b2[c] - mean * sc;
    short4 zz = ((const short4*)z2)[idx];
    float4 o  = ((const float4*)out)[idx];
    o.x = (float)((double)zz.x * 0.5 * sc + sh + (double)o.x);
    o.y = (float)((double)zz.y * 0.5 * sc + sh + (double)o.y);
    o.z = (float)((double)zz.z * 0.5 * sc + sh + (double)o.z);
    o.w = (float)((double)zz.w * 0.5 * sc + sh + (double)o.w);
    ((float4*)out)[idx] = o;
}

// ---------------------------------------------------------------------------
extern "C" void kernel_launch(void* const* d_in, const int* in_sizes, int n_in,
                              void* d_out, int out_size, void* d_ws, size_t ws_size,
                              hipStream_t stream) {
    const float* x  = (const float*)d_in[0];
    const float* w1 = (const float*)d_in[1];
    const float* g1 = (const float*)d_in[2];
    const float* b1 = (const float*)d_in[3];
    const float* w2 = (const float*)d_in[4];
    const float* g2 = (const float*)d_in[5];
    const float* b2 = (const float*)d_in[6];
    float* out = (float*)d_out;

    char* ws = (char*)d_ws;
    auto alloc = [&](size_t bytes) -> char* {
        char* p = ws;
        ws += (bytes + 255) & ~(size_t)255;
        return p;
    };

    unsigned long long* xbits   = (unsigned long long*)alloc((size_t)NB * NG * HW * 8);
    unsigned long long* wbits1  = (unsigned long long*)alloc((size_t)NC * 9 * 8);
    unsigned long long* w2bits  = (unsigned long long*)alloc((size_t)NC * 4 * 8);
    unsigned long long* gstat   = (unsigned long long*)alloc(1024 * 8);
    short*              y1      = (short*)alloc((size_t)NOUT * 2);
    short*              z2buf   = (short*)alloc((size_t)NOUT * 2);

    const int T = 256;

    pack_all_k<<<PXBLK + 13,     T, 0, stream>>>(x, w1, w2, xbits, wbits1, w2bits, gstat);
    conv1_lds <<<NB * NG * 7,    T, 0, stream>>>(xbits, wbits1, y1, gstat);
    x1_lds    <<<NB * NC,        T, 0, stream>>>(y1, x, gstat, g1, b1, out);
    conv2f_lds<<<NB * 14,        T, 0, stream>>>(out, w2bits, z2buf, gstat);
    final_k   <<<(NOUT / 4) / T, T, 0, stream>>>(z2buf, gstat, g2, b2, out);
}

// Round 24
// 115.639 us; speedup vs baseline: 2.5774x; 1.0006x over previous
//
#include <hip/hip_runtime.h>
#include <cstdint>
#include <math.h>

#define NB 32
#define NC 256
#define NH 56
#define NW 56
#define OHH 28
#define OWW 28
#define NG 4
#define EPSV 1e-5

static constexpr int HW   = NH * NW;       // 3136
static constexpr int OHW  = OHH * OWW;     // 784
static constexpr int NOUT = NB * NC * OHW; // 6422528
static constexpr int NRED = NB * OHW;      // 25088
static constexpr int QW   = OHW / 4;       // 196
static constexpr int PTILE = 56;           // conv2 pixel tile (784 = 14*56)
static constexpr int PXBLK = NB * NG * HW / 4 / 256;  // 6272 pack_x blocks

// Hedge zone (validated round 9): |x1| < TAU1 -> contribute 0.5*sign to conv2.
#define TAU1 2e-5f

// gstat layout (u64): [0..255] sum1, [256..511] sumsq1, [512..767] sum2, [768..1023] sumsq2

// ---------------------------------------------------------------------------
// K1: MERGED pack: blocks [0,6272) pack x sign bits (float4, 4 px/thread);
// blocks [6272,6285) pack w1+w2 sign bits and zero the gstat accumulators.
__global__ void pack_all_k(const float* __restrict__ x,
                           const float* __restrict__ w1,
                           const float* __restrict__ w2,
                           unsigned long long* __restrict__ xbits,
                           unsigned long long* __restrict__ wbits,
                           unsigned long long* __restrict__ w2bits,
                           unsigned long long* __restrict__ gstat) {
    if (blockIdx.x < PXBLK) {
        int idx = blockIdx.x * blockDim.x + threadIdx.x; // NB*NG*HW/4
        int wq = idx % (NW / 4);
        int h  = (idx / (NW / 4)) % NH;
        int g  = (idx / (NW / 4 * NH)) % NG;
        int b  = idx / (NW / 4 * NH * NG);
        const float* xp = x + (((size_t)b * NC + g * 64) * NH + h) * NW + wq * 4;
        unsigned long long b0 = 0, b1 = 0, b2 = 0, b3 = 0;
#pragma unroll
        for (int ci = 0; ci < 64; ++ci) {
            float4 v = *(const float4*)(xp + (size_t)ci * HW);
            b0 |= (unsigned long long)(v.x >= 0.0f) << ci;
            b1 |= (unsigned long long)(v.y >= 0.0f) << ci;
            b2 |= (unsigned long long)(v.z >= 0.0f) << ci;
            b3 |= (unsigned long long)(v.w >= 0.0f) << ci;
        }
        unsigned long long* dst = xbits + ((size_t)(b * NG + g) * NH + h) * NW + wq * 4;
        dst[0] = b0; dst[1] = b1; dst[2] = b2; dst[3] = b3;
    } else {
        int idx = (blockIdx.x - PXBLK) * blockDim.x + threadIdx.x; // 0..3327
        if (idx < 1024) gstat[idx] = 0ull;
        if (idx < 2304) {
            int tap = idx % 9;
            int co  = idx / 9;
            const float* wp = w1 + (size_t)co * 64 * 9 + tap;
            unsigned long long bits = 0;
#pragma unroll
            for (int ci = 0; ci < 64; ++ci)
                bits |= (unsigned long long)(wp[ci * 9] >= 0.0f) << ci;
            wbits[idx] = bits;
        } else {
            int i2 = idx - 2304;         // 0..1023
            int k  = i2 % 4;
            int co = i2 / 4;
            const float* p = w2 + (size_t)co * 256 + k * 64;
            unsigned long long bits = 0;
#pragma unroll
            for (int ci = 0; ci < 64; ++ci)
                bits |= (unsigned long long)(p[ci] >= 0.0f) << ci;
            w2bits[i2] = bits;
        }
    }
}

// K2: LDS-broadcast popcount grouped 3x3 conv + FUSED BN1 stats (atomics).
__global__ void __launch_bounds__(256) conv1_lds(
        const unsigned long long* __restrict__ xbits,
        const unsigned long long* __restrict__ wbits,
        short* __restrict__ y1,
        unsigned long long* __restrict__ gstat) {
    int blk = blockIdx.x;          // NB*NG*7
    int s7  = blk % 7;             // strip: output rows s7*4 .. s7*4+3
    int g   = (blk / 7) & 3;
    int b   = blk / 28;
    int tid = threadIdx.x;
    int co  = tid & 63;            // lane = channel in group
    int ohl = tid >> 6;            // 0..3

    __shared__ unsigned long long xs[9 * 57];      // [row][col0 = iw=-1 pad]
    __shared__ short ybuf[64][114];                // 112 data + 2 pad
    __shared__ int ssum[4][64];
    __shared__ int ssumsq[4][64];

    int ih0 = s7 * 8 - 1;
    const unsigned long long* xb = xbits + (size_t)(b * NG + g) * HW;
    for (int i = tid; i < 9 * 57; i += 256) {
        int r  = i / 57;
        int cc = i % 57;
        int ih = ih0 + r;
        unsigned long long v = 0;
        if (cc > 0 && (unsigned)ih < (unsigned)NH) v = xb[ih * NW + (cc - 1)];
        xs[i] = v;
    }
    __syncthreads();

    int coG = g * 64 + co;
    const unsigned long long* wb = wbits + coG * 9;
    unsigned long long w0 = wb[0], w1 = wb[1], w2 = wb[2],
                       w3 = wb[3], w4 = wb[4], w5 = wb[5],
                       w6 = wb[6], w7 = wb[7], w8 = wb[8];
    int oh = s7 * 4 + ohl;
    int t0 = 64 - 2 * __popcll(w0), t1 = 64 - 2 * __popcll(w1), t2 = 64 - 2 * __popcll(w2);
    int t3 = 64 - 2 * __popcll(w3), t6 = 64 - 2 * __popcll(w6);
    int base9   = 576 - ((oh == 0) ? (t0 + t1 + t2) : 0);
    int colcorr = t3 + t6 + ((oh == 0) ? 0 : t0);

    const unsigned long long* r0 = xs + (2 * ohl + 0) * 57;
    const unsigned long long* r1 = xs + (2 * ohl + 1) * 57;
    const unsigned long long* r2 = xs + (2 * ohl + 2) * 57;
    short* yrow = &ybuf[co][ohl * 28];
    int isum = 0, isumsq = 0;
    for (int ow = 0; ow < OWW; ++ow) {
        int cbase = ow * 2;
        int acc = __popcll(r0[cbase] ^ w0) + __popcll(r0[cbase + 1] ^ w1) + __popcll(r0[cbase + 2] ^ w2)
                + __popcll(r1[cbase] ^ w3) + __popcll(r1[cbase + 1] ^ w4) + __popcll(r1[cbase + 2] ^ w5)
                + __popcll(r2[cbase] ^ w6) + __popcll(r2[cbase + 1] ^ w7) + __popcll(r2[cbase + 2] ^ w8);
        int y = base9 - ((ow == 0) ? colcorr : 0) - 2 * acc;
        yrow[ow] = (short)y;
        isum   += y;
        isumsq += y * y;
    }
    ssum[ohl][co]   = isum;
    ssumsq[ohl][co] = isumsq;
    __syncthreads();

    for (int i = tid; i < 64 * 112; i += 256) {
        int c2 = i / 112;
        int j  = i % 112;
        y1[((size_t)(b * NC + g * 64 + c2) * OHH + s7 * 4) * OWW + j] =
            ybuf[c2][j];
    }
    if (ohl == 0) {
        long long s  = (long long)ssum[0][co] + ssum[1][co] + ssum[2][co] + ssum[3][co];
        long long sq = (long long)ssumsq[0][co] + ssumsq[1][co] + ssumsq[2][co] + ssumsq[3][co];
        atomicAdd(&gstat[coG],       (unsigned long long)s);
        atomicAdd(&gstat[256 + coG], (unsigned long long)sq);
    }
}

// K3: x1 = BN1(y1) + maxpool3x3s2p1(x); BN1 scale/shift inline from exact sums.
__global__ void __launch_bounds__(256) x1_lds(
        const short* __restrict__ y1,
        const float* __restrict__ x,
        const unsigned long long* __restrict__ gstat,
        const float* __restrict__ g1,
        const float* __restrict__ b1,
        float* __restrict__ out) {
    int blk = blockIdx.x;            // b*NC + c
    int c   = blk & 255;
    int tid = threadIdx.x;
    __shared__ float xs[HW];         // 12.5 KB
    const float4* xp4 = (const float4*)(x + (size_t)blk * HW);
    float4* xs4 = (float4*)xs;
    for (int i = tid; i < HW / 4; i += 256) xs4[i] = xp4[i];
    __syncthreads();
    long long s1v = (long long)gstat[c];
    long long s2v = (long long)gstat[256 + c];
    double n    = (double)NRED;
    double mean = (double)s1v / n;
    double var  = (double)s2v / n - mean * mean;
    double inv  = 1.0 / sqrt(var + EPSV);
    double sc   = (double)g1[c] * inv;
    double sh   = (double)b1[c] - mean * sc;
    const short* yp = y1 + (size_t)blk * OHW;
    float* op = out + (size_t)blk * OHW;
    for (int s = tid; s < OHW; s += 256) {
        int oh = s / OWW, ow = s % OWW;
        float m = -3.4e38f;
#pragma unroll
        for (int kh = 0; kh < 3; ++kh) {
            int ih = oh * 2 - 1 + kh;
            if ((unsigned)ih >= (unsigned)NH) continue;
#pragma unroll
            for (int kw = 0; kw < 3; ++kw) {
                int iw = ow * 2 - 1 + kw;
                if ((unsigned)iw >= (unsigned)NW) continue;
                m = fmaxf(m, xs[ih * NW + iw]);
            }
        }
        op[s] = (float)((double)yp[s] * sc + sh + (double)m);
    }
}

// K4: FUSED ballot-pack + popcount 1x1 conv + BN2 stats.
// LDS-compact: stage computes 2-bit codes (sign<<1 | hedge) -> bytes, ballots
// read the bytes, and the z-transpose reduce buffer ALIASES the dead code
// region. ~33 KB LDS -> 4 blocks/CU.
__global__ void __launch_bounds__(256) conv2f_lds(
        const float* __restrict__ x1,
        const unsigned long long* __restrict__ w2bits,
        short* __restrict__ z2,
        unsigned long long* __restrict__ gstat) {
    int blk  = blockIdx.x;         // b*14 + t
    int t    = blk % 14;
    int b    = blk / 14;
    int tid  = threadIdx.x;
    int lane = tid & 63;
    int w    = tid >> 6;           // 0..3 = channel group
    int s0   = t * PTILE;
    __shared__ __align__(16) char smemU[NC * (PTILE + 1) * 2];   // 29.2 KB union
    unsigned char (*code)[PTILE + 1] = (unsigned char (*)[PTILE + 1])smemU; // stage+ballot
    short (*ztr)[PTILE + 1]          = (short (*)[PTILE + 1])smemU;         // sweep+reduce
    __shared__ unsigned long long bitsL[4][PTILE];
    __shared__ unsigned long long hedgeL[4][PTILE];

    {   // stage: thread = channel; read 56 floats, store 2-bit codes
        const float4* src = (const float4*)(x1 + ((size_t)b * NC + tid) * OHW + s0);
        unsigned char* dst = code[tid];
#pragma unroll
        for (int q = 0; q < 14; ++q) {
            float4 v = src[q];
            dst[q * 4 + 0] = (unsigned char)((v.x >= 0.0f ? 2 : 0) | (fabsf(v.x) < TAU1 ? 1 : 0));
            dst[q * 4 + 1] = (unsigned char)((v.y >= 0.0f ? 2 : 0) | (fabsf(v.y) < TAU1 ? 1 : 0));
            dst[q * 4 + 2] = (unsigned char)((v.z >= 0.0f ? 2 : 0) | (fabsf(v.z) < TAU1 ? 1 : 0));
            dst[q * 4 + 3] = (unsigned char)((v.w >= 0.0f ? 2 : 0) | (fabsf(v.w) < TAU1 ? 1 : 0));
        }
    }
    __syncthreads();

    for (int px = 0; px < PTILE; ++px) {
        unsigned int cv = code[w * 64 + lane][px];
        unsigned long long bb = __ballot((cv & 2u) != 0u);
        unsigned long long hh = __ballot((cv & 1u) != 0u);
        if (lane == 0) { bitsL[w][px] = bb; hedgeL[w][px] = hh; }
    }
    __syncthreads();               // code dead beyond this point; ztr takes over

    for (int it = 0; it < 64; ++it) {
        int co = it * 4 + w;
        const unsigned long long* wb = w2bits + co * 4;
        unsigned long long wv0 = wb[0], wv1 = wb[1], wv2 = wb[2], wv3 = wb[3];
        if (lane < PTILE) {
            unsigned long long d0 = bitsL[0][lane] ^ wv0, d1 = bitsL[1][lane] ^ wv1,
                               d2 = bitsL[2][lane] ^ wv2, d3 = bitsL[3][lane] ^ wv3;
            unsigned long long h0 = hedgeL[0][lane], h1 = hedgeL[1][lane],
                               h2 = hedgeL[2][lane], h3 = hedgeL[3][lane];
            int full = 256 - 2 * (__popcll(d0) + __popcll(d1) + __popcll(d2) + __popcll(d3));
            int hcorr = __popcll(h0) + __popcll(h1) + __popcll(h2) + __popcll(h3)
                      - 2 * (__popcll(h0 & d0) + __popcll(h1 & d1) +
                             __popcll(h2 & d2) + __popcll(h3 & d3));
            int zz = 2 * full - hcorr;
            z2[((size_t)b * NC + co) * OHW + s0 + lane] = (short)zz;
            ztr[co][lane] = (short)zz;
        }
    }
    __syncthreads();

    // per-channel partial stats: thread = channel; register reduce from LDS
    {
        int zsum = 0, zsq = 0;
#pragma unroll
        for (int j = 0; j < PTILE; ++j) {
            int zz = ztr[tid][j];
            zsum += zz;
            zsq  += zz * zz;
        }
        atomicAdd(&gstat[512 + tid], (unsigned long long)(long long)zsum);
        atomicAdd(&gstat[768 + tid], (unsigned long long)zsq);
    }
}

// K5: out = BN2(z) + x1; BN2 scale/shift inline from exact sums (vdiv=2).
__global__ void final_k(const short* __restrict__ z2,
                        const unsigned long long* __restrict__ gstat,
                        const float* __restrict__ g2,
                        const float* __restrict__ b2,
                        float* __restrict__ out) {
    int idx = blockIdx.x * blockDim.x + threadIdx.x;   // NOUT/4
    int c = (idx / QW) % NC;
    long long s1v = (long long)gstat[512 + c];
    long long s2v = (long long)gstat[768 + c];
    double n    = (double)NRED;
    double mean = (double)s1v / (n * 2.0);
    double var  = (double)s2v / (n * 2.0 * 2.0) - mean * mean;
    double inv  = 1.0 / sqrt(var + EPSV);
    double sc   = (double)g2[c] * inv;
    double sh   = (double)b2[c] - mean * sc;
    short4 zz = ((const short4*)z2)[idx];
    float4 o  = ((const float4*)out)[idx];
    o.x = (float)((double)zz.x * 0.5 * sc + sh + (double)o.x);
    o.y = (float)((double)zz.y * 0.5 * sc + sh + (double)o.y);
    o.z = (float)((double)zz.z * 0.5 * sc + sh + (double)o.z);
    o.w = (float)((double)zz.w * 0.5 * sc + sh + (double)o.w);
    ((float4*)out)[idx] = o;
}

// ---------------------------------------------------------------------------
extern "C" void kernel_launch(void* const* d_in, const int* in_sizes, int n_in,
                              void* d_out, int out_size, void* d_ws, size_t ws_size,
                              hipStream_t stream) {
    const float* x  = (const float*)d_in[0];
    const float* w1 = (const float*)d_in[1];
    const float* g1 = (const float*)d_in[2];
    const float* b1 = (const float*)d_in[3];
    const float* w2 = (const float*)d_in[4];
    const float* g2 = (const float*)d_in[5];
    const float* b2 = (const float*)d_in[6];
    float* out = (float*)d_out;

    char* ws = (char*)d_ws;
    auto alloc = [&](size_t bytes) -> char* {
        char* p = ws;
        ws += (bytes + 255) & ~(size_t)255;
        return p;
    };

    unsigned long long* xbits   = (unsigned long long*)alloc((size_t)NB * NG * HW * 8);
    unsigned long long* wbits1  = (unsigned long long*)alloc((size_t)NC * 9 * 8);
    unsigned long long* w2bits  = (unsigned long long*)alloc((size_t)NC * 4 * 8);
    unsigned long long* gstat   = (unsigned long long*)alloc(1024 * 8);
    short*              y1      = (short*)alloc((size_t)NOUT * 2);
    short*              z2buf   = (short*)alloc((size_t)NOUT * 2);

    const int T = 256;

    pack_all_k<<<PXBLK + 13,     T, 0, stream>>>(x, w1, w2, xbits, wbits1, w2bits, gstat);
    conv1_lds <<<NB * NG * 7,    T, 0, stream>>>(xbits, wbits1, y1, gstat);
    x1_lds    <<<NB * NC,        T, 0, stream>>>(y1, x, gstat, g1, b1, out);
    conv2f_lds<<<NB * 14,        T, 0, stream>>>(out, w2bits, z2buf, gstat);
    final_k   <<<(NOUT / 4) / T, T, 0, stream>>>(z2buf, gstat, g2, b2, out);
}